// Round 4
// baseline (406.209 us; speedup 1.0000x reference)
//
#include <hip/hip_runtime.h>
#include <hip/hip_bf16.h>
#include <stdint.h>

#define CIN   448
#define DP    100
#define NPIX  4096
#define LNUM  4096
#define KQ    5050      // packed upper-triangle columns
#define KLIN  5150      // + 100 linear columns
#define KTOT  5184      // padded to 81*64
#define KSTEPS (KTOT / 64)
#define OUTHW 256

typedef _Float16 f16_t;
typedef _Float16 f16x8 __attribute__((ext_vector_type(8)));
typedef float    f32x4 __attribute__((ext_vector_type(4)));

static __device__ __forceinline__ int tri_off(int d) { return (d * (201 - d)) >> 1; }

static __device__ __forceinline__ void unpack_tri(int k, int& d, int& e) {
    int dd = (int)((201.0f - sqrtf(40401.0f - 8.0f * (float)k)) * 0.5f);
    if (dd < 0) dd = 0;
    if (dd > 99) dd = 99;
    while (tri_off(dd + 1) <= k) ++dd;
    while (tri_off(dd) > k) --dd;
    d = dd;
    e = dd + (k - tri_off(dd));
}

static __device__ __forceinline__ unsigned f2u(float x) {
    unsigned b = __float_as_uint(x);
    return (b & 0x80000000u) ? ~b : (b | 0x80000000u);
}
static __device__ __forceinline__ float u2f(unsigned u) {
    unsigned b = (u & 0x80000000u) ? (u & 0x7FFFFFFFu) : ~u;
    return __uint_as_float(b);
}

// ---------------- kernel 1: projection f[n,d] = feat[:,n] . w[d,:] + b[d] ----------------
__global__ void k_proj(const float* __restrict__ feat, const float* __restrict__ w,
                       const float* __restrict__ b, float* __restrict__ f) {
    int gid = blockIdx.x * 256 + threadIdx.x;   // 409600 = 4096*100
    int n = gid & 4095;
    int d = gid >> 12;
    float acc = b[d];
    const float* wd = w + d * CIN;
    #pragma unroll 4
    for (int c = 0; c < CIN; ++c) acc += feat[c * 4096 + n] * wd[c];
    f[n * DP + d] = acc;
}

// ---------------- kernel 2: build A (N x KTOT, f16) ----------------
__global__ __launch_bounds__(256) void k_buildA(const float* __restrict__ f, f16_t* __restrict__ A) {
    __shared__ float fr[DP];
    int n = blockIdx.x;
    int t = threadIdx.x;
    if (t < DP) fr[t] = f[n * DP + t];
    __syncthreads();
    f16_t* Arow = A + (size_t)n * KTOT;
    for (int k = t; k < KTOT; k += 256) {
        float v;
        if (k < KQ) {
            int d, e;
            unpack_tri(k, d, e);
            v = fr[d] * fr[e];
        } else if (k < KLIN) {
            v = fr[k - KQ];          // f_d
        } else {
            v = 0.0f;
        }
        Arow[k] = (f16_t)v;
    }
}

// ---------------- kernel 3: build B (L x KTOT, f16) + const[l] ----------------
__global__ __launch_bounds__(256) void k_buildB(const float* __restrict__ icov, const float* __restrict__ mean,
                                                f16_t* __restrict__ Bm, float* __restrict__ constl) {
    __shared__ float ic[DP * DP];
    __shared__ float ml[DP];
    __shared__ float wv[DP];
    __shared__ float part[DP];
    int l = blockIdx.x;
    int t = threadIdx.x;
    const float* src = icov + (size_t)l * DP * DP;
    for (int i = t; i < DP * DP; i += 256) ic[i] = src[i];
    if (t < DP) ml[t] = mean[t * LNUM + l];
    __syncthreads();
    if (t < DP) {
        float icm = 0.f, ictm = 0.f;
        for (int e = 0; e < DP; ++e) {
            icm  += ic[t * DP + e] * ml[e];
            ictm += ic[e * DP + t] * ml[e];
        }
        wv[t]   = icm + ictm;        // (S m)_t  with S = IC + IC^T
        part[t] = ml[t] * icm;       // for m^T IC m
    }
    __syncthreads();
    if (t == 0) {
        float c = 0.f;
        for (int d = 0; d < DP; ++d) c += part[d];
        constl[l] = c;               // m^T IC m
    }
    f16_t* Brow = Bm + (size_t)l * KTOT;
    for (int k = t; k < KTOT; k += 256) {
        float v;
        if (k < KQ) {
            int d, e;
            unpack_tri(k, d, e);
            float s = ic[d * DP + e] + ic[e * DP + d];
            v = (d == e) ? 0.5f * s : s;
        } else if (k < KLIN) {
            v = -wv[k - KQ];         // -(S m)_d, pairs with f_d
        } else {
            v = 0.0f;
        }
        Brow[k] = (f16_t)v;
    }
}

// ---------------- kernel 4a: init per-row min ----------------
__global__ void k_init(unsigned* __restrict__ mind) {
    int i = blockIdx.x * 256 + threadIdx.x;
    if (i < NPIX) mind[i] = 0xFFFFFFFFu;
}

// ---------------- kernel 4: MFMA GEMM (dist = A.B^T + const) with fused row-min ----------------
__global__ __launch_bounds__(256, 2) void k_gemm(const f16_t* __restrict__ A, const f16_t* __restrict__ Bm,
                                                 const float* __restrict__ constl, unsigned* __restrict__ mind) {
    __shared__ __align__(16) f16_t sA[128 * 64];
    __shared__ __align__(16) f16_t sB[128 * 64];

    int bid = blockIdx.x;
    int pid = ((bid & 7) << 7) | (bid >> 3);       // XCD swizzle (1024 % 8 == 0, bijective)
    int group = pid >> 8;
    int pin = pid & 255;
    int bm = group * 8 + (pin & 7);
    int bn = pin >> 3;

    int t = threadIdx.x;
    int lane = t & 63;
    int w = t >> 6;
    int wr = w >> 1, wc = w & 1;

    f32x4 acc[4][4];
    #pragma unroll
    for (int i = 0; i < 4; ++i)
        #pragma unroll
        for (int j = 0; j < 4; ++j) acc[i][j] = (f32x4){0.f, 0.f, 0.f, 0.f};

    const f16_t* Abase = A + (size_t)(bm * 128) * KTOT;
    const f16_t* Bbase = Bm + (size_t)(bn * 128) * KTOT;
    int trow = t >> 3;          // 0..31
    int tcol = (t & 7) * 8;     // element offset within 64

    for (int kt = 0; kt < KSTEPS; ++kt) {
        int kofs = kt * 64;
        f16x8 ra[4], rb[4];
        #pragma unroll
        for (int i = 0; i < 4; ++i) {
            int r = i * 32 + trow;
            ra[i] = *(const f16x8*)(Abase + (size_t)r * KTOT + kofs + tcol);
            rb[i] = *(const f16x8*)(Bbase + (size_t)r * KTOT + kofs + tcol);
        }
        __syncthreads();   // previous iteration's MFMA reads done before overwrite
        #pragma unroll
        for (int i = 0; i < 4; ++i) {
            int r = i * 32 + trow;
            *(f16x8*)&sA[r * 64 + tcol] = ra[i];
            *(f16x8*)&sB[r * 64 + tcol] = rb[i];
        }
        __syncthreads();   // tile ready
        #pragma unroll
        for (int kk = 0; kk < 2; ++kk) {
            f16x8 afr[4], bfr[4];
            int klo = kk * 32 + (lane >> 4) * 8;
            #pragma unroll
            for (int mi = 0; mi < 4; ++mi)
                afr[mi] = *(const f16x8*)&sA[(wr * 64 + mi * 16 + (lane & 15)) * 64 + klo];
            #pragma unroll
            for (int ni = 0; ni < 4; ++ni)
                bfr[ni] = *(const f16x8*)&sB[(wc * 64 + ni * 16 + (lane & 15)) * 64 + klo];
            #pragma unroll
            for (int mi = 0; mi < 4; ++mi)
                #pragma unroll
                for (int ni = 0; ni < 4; ++ni)
                    acc[mi][ni] = __builtin_amdgcn_mfma_f32_16x16x32_f16(afr[mi], bfr[ni], acc[mi][ni], 0, 0, 0);
        }
    }

    // epilogue: dist = acc + const[col]; min over this block's cols per row; atomicMin
    int colbase = bn * 128 + wc * 64 + (lane & 15);
    float cl[4];
    #pragma unroll
    for (int ni = 0; ni < 4; ++ni) cl[ni] = constl[colbase + ni * 16];
    #pragma unroll
    for (int mi = 0; mi < 4; ++mi) {
        #pragma unroll
        for (int j = 0; j < 4; ++j) {
            float v = 1e30f;
            #pragma unroll
            for (int ni = 0; ni < 4; ++ni) v = fminf(v, acc[mi][ni][j] + cl[ni]);
            #pragma unroll
            for (int s = 1; s < 16; s <<= 1) v = fminf(v, __shfl_xor(v, s, 64));
            if ((lane & 15) == 0) {
                int row = bm * 128 + wr * 64 + mi * 16 + (lane >> 4) * 4 + j;
                atomicMin(&mind[row], f2u(v));
            }
        }
    }
}

// ---------------- kernel 5: global min/max of mind ----------------
__global__ void k_minmax(const unsigned* __restrict__ mind, float* __restrict__ gmm) {
    __shared__ float smin[256], smax[256];
    int t = threadIdx.x;
    float vmin = 1e30f, vmax = -1e30f;
    for (int i = t; i < NPIX; i += 256) {
        float v = u2f(mind[i]);
        vmin = fminf(vmin, v);
        vmax = fmaxf(vmax, v);
    }
    smin[t] = vmin; smax[t] = vmax;
    __syncthreads();
    for (int s = 128; s > 0; s >>= 1) {
        if (t < s) {
            smin[t] = fminf(smin[t], smin[t + s]);
            smax[t] = fmaxf(smax[t], smax[t + s]);
        }
        __syncthreads();
    }
    if (t == 0) { gmm[0] = smin[0]; gmm[1] = smax[0]; }
}

// ---------------- kernel 6: normalize + bilinear upsample 64->256 (FLOAT32 output) ----------------
__global__ void k_upsample(const unsigned* __restrict__ mind, const float* __restrict__ gmm,
                           float* __restrict__ out) {
    int gid = blockIdx.x * 256 + threadIdx.x;   // 65536
    int i = gid >> 8, j = gid & 255;
    float gmin = gmm[0];
    float scale = 1.0f / (gmm[1] - gmm[0] + 1e-8f);
    float x = fminf(fmaxf(j * 0.25f - 0.375f, 0.0f), 63.0f);
    float y = fminf(fmaxf(i * 0.25f - 0.375f, 0.0f), 63.0f);
    int x0 = (int)x, y0 = (int)y;
    int x1 = min(x0 + 1, 63), y1 = min(y0 + 1, 63);
    float fx = x - x0, fy = y - y0;
    float v00 = u2f(mind[y0 * 64 + x0]), v01 = u2f(mind[y0 * 64 + x1]);
    float v10 = u2f(mind[y1 * 64 + x0]), v11 = u2f(mind[y1 * 64 + x1]);
    float v = v00 * (1.f - fy) * (1.f - fx) + v01 * (1.f - fy) * fx
            + v10 * fy * (1.f - fx) + v11 * fy * fx;
    out[gid] = (v - gmin) * scale;
}

// ---------------- diagnostic: ws too small -> uniform 0.25 output (absmax ~0.70) ----------------
__global__ void k_diag(float* __restrict__ out) {
    int gid = blockIdx.x * 256 + threadIdx.x;
    out[gid] = 0.25f;
}

extern "C" void kernel_launch(void* const* d_in, const int* in_sizes, int n_in,
                              void* d_out, int out_size, void* d_ws, size_t ws_size,
                              hipStream_t stream) {
    const float* feat = (const float*)d_in[0];
    const float* pw   = (const float*)d_in[1];
    const float* pb   = (const float*)d_in[2];
    const float* mean = (const float*)d_in[3];
    const float* icov = (const float*)d_in[4];

    size_t need = 0;
    auto count = [&need](size_t bytes) { need = ((need + 255) & ~(size_t)255) + bytes; };
    count((size_t)NPIX * DP * 4);
    count((size_t)NPIX * KTOT * 2);
    count((size_t)LNUM * KTOT * 2);
    count((size_t)LNUM * 4);
    count((size_t)NPIX * 4);
    count(2 * 4);
    if (ws_size < need) {
        k_diag<<<256, 256, 0, stream>>>((float*)d_out);
        return;
    }

    char* ws = (char*)d_ws;
    size_t off = 0;
    auto alloc = [&](size_t bytes) -> void* {
        off = (off + 255) & ~(size_t)255;
        void* p = ws + off;
        off += bytes;
        return p;
    };
    float*    f      = (float*)alloc((size_t)NPIX * DP * 4);
    f16_t*    Amat   = (f16_t*)alloc((size_t)NPIX * KTOT * 2);
    f16_t*    Bmat   = (f16_t*)alloc((size_t)LNUM * KTOT * 2);
    float*    constl = (float*)alloc((size_t)LNUM * 4);
    unsigned* mind   = (unsigned*)alloc((size_t)NPIX * 4);
    float*    gmm    = (float*)alloc(2 * 4);

    k_proj    <<<1600, 256, 0, stream>>>(feat, pw, pb, f);
    k_buildA  <<<NPIX, 256, 0, stream>>>(f, Amat);
    k_buildB  <<<LNUM, 256, 0, stream>>>(icov, mean, Bmat, constl);
    k_init    <<<16, 256, 0, stream>>>(mind);
    k_gemm    <<<1024, 256, 0, stream>>>(Amat, Bmat, constl, mind);
    k_minmax  <<<1, 256, 0, stream>>>(mind, gmm);
    k_upsample<<<256, 256, 0, stream>>>(mind, gmm, (float*)d_out);
}

// Round 5
// 319.659 us; speedup vs baseline: 1.2708x; 1.2708x over previous
//
#include <hip/hip_runtime.h>
#include <hip/hip_bf16.h>
#include <stdint.h>

#define CIN   448
#define DP    100
#define NPIX  4096
#define LNUM  4096
#define KQ    5050      // packed upper-triangle columns
#define KLIN  5150      // + 100 linear columns
#define KTOT  5184      // padded to 81*64
#define KSTEPS (KTOT / 64)
#define OUTHW 256

typedef _Float16 f16_t;
typedef _Float16 f16x8 __attribute__((ext_vector_type(8)));
typedef float    f32x4 __attribute__((ext_vector_type(4)));

// swizzled f16 index inside a 128x64 tile: element (r, kin)
static __device__ __forceinline__ int swz_idx(int r, int kin) {
    return r * 64 + ((kin & 56) ^ ((r & 7) << 3)) + (kin & 7);
}

static __device__ __forceinline__ int tri_off(int d) { return (d * (201 - d)) >> 1; }

static __device__ __forceinline__ void unpack_tri(int k, int& d, int& e) {
    int dd = (int)((201.0f - sqrtf(40401.0f - 8.0f * (float)k)) * 0.5f);
    if (dd < 0) dd = 0;
    if (dd > 99) dd = 99;
    while (tri_off(dd + 1) <= k) ++dd;
    while (tri_off(dd) > k) --dd;
    d = dd;
    e = dd + (k - tri_off(dd));
}

static __device__ __forceinline__ unsigned f2u(float x) {
    unsigned b = __float_as_uint(x);
    return (b & 0x80000000u) ? ~b : (b | 0x80000000u);
}
static __device__ __forceinline__ float u2f(unsigned u) {
    unsigned b = (u & 0x80000000u) ? (u & 0x7FFFFFFFu) : ~u;
    return __uint_as_float(b);
}

static __device__ __forceinline__ void gload_lds16(const f16_t* g, f16_t* l) {
    __builtin_amdgcn_global_load_lds((const __attribute__((address_space(1))) unsigned*)g,
                                     (__attribute__((address_space(3))) unsigned*)l,
                                     16, 0, 0);
}

// ---------------- kernel 1: projection f[n,d] = feat[:,n] . w[d,:] + b[d] ----------------
__global__ void k_proj(const float* __restrict__ feat, const float* __restrict__ w,
                       const float* __restrict__ b, float* __restrict__ f) {
    int gid = blockIdx.x * 256 + threadIdx.x;   // 409600 = 4096*100
    int n = gid & 4095;
    int d = gid >> 12;
    float acc = b[d];
    const float* wd = w + d * CIN;
    #pragma unroll 4
    for (int c = 0; c < CIN; ++c) acc += feat[c * 4096 + n] * wd[c];
    f[n * DP + d] = acc;
}

// ---------------- kernel 2: build A, tiled+swizzled (32 mtiles x 81 ktiles x 8192 f16) ----------------
__global__ __launch_bounds__(256) void k_buildA(const float* __restrict__ f, f16_t* __restrict__ A) {
    __shared__ float fr[DP];
    int n = blockIdx.x;
    int t = threadIdx.x;
    if (t < DP) fr[t] = f[n * DP + t];
    __syncthreads();
    int r  = n & 127;
    int bm = n >> 7;
    f16_t* tileBase = A + (size_t)bm * KSTEPS * 8192;
    for (int k = t; k < KTOT; k += 256) {
        float v;
        if (k < KQ) {
            int d, e;
            unpack_tri(k, d, e);
            v = fr[d] * fr[e];
        } else if (k < KLIN) {
            v = fr[k - KQ];          // f_d
        } else {
            v = 0.0f;
        }
        int kt = k >> 6, kin = k & 63;
        tileBase[kt * 8192 + swz_idx(r, kin)] = (f16_t)v;
    }
}

// ---------------- kernel 3: build B, tiled+swizzled + const[l] ----------------
__global__ __launch_bounds__(256) void k_buildB(const float* __restrict__ icov, const float* __restrict__ mean,
                                                f16_t* __restrict__ Bm, float* __restrict__ constl) {
    __shared__ float ic[DP * DP];
    __shared__ float ml[DP];
    __shared__ float wv[DP];
    __shared__ float part[DP];
    int l = blockIdx.x;
    int t = threadIdx.x;
    const float* src = icov + (size_t)l * DP * DP;
    for (int i = t; i < DP * DP; i += 256) ic[i] = src[i];
    if (t < DP) ml[t] = mean[t * LNUM + l];
    __syncthreads();
    if (t < DP) {
        float icm = 0.f, ictm = 0.f;
        for (int e = 0; e < DP; ++e) {
            icm  += ic[t * DP + e] * ml[e];
            ictm += ic[e * DP + t] * ml[e];
        }
        wv[t]   = icm + ictm;        // (S m)_t  with S = IC + IC^T
        part[t] = ml[t] * icm;       // for m^T IC m
    }
    __syncthreads();
    if (t == 0) {
        float c = 0.f;
        for (int d = 0; d < DP; ++d) c += part[d];
        constl[l] = c;               // m^T IC m
    }
    int r  = l & 127;
    int bn = l >> 7;
    f16_t* tileBase = Bm + (size_t)bn * KSTEPS * 8192;
    for (int k = t; k < KTOT; k += 256) {
        float v;
        if (k < KQ) {
            int d, e;
            unpack_tri(k, d, e);
            float s = ic[d * DP + e] + ic[e * DP + d];
            v = (d == e) ? 0.5f * s : s;
        } else if (k < KLIN) {
            v = -wv[k - KQ];         // -(S m)_d, pairs with f_d
        } else {
            v = 0.0f;
        }
        int kt = k >> 6, kin = k & 63;
        tileBase[kt * 8192 + swz_idx(r, kin)] = (f16_t)v;
    }
}

// ---------------- kernel 4a: init per-row min ----------------
__global__ void k_init(unsigned* __restrict__ mind) {
    int i = blockIdx.x * 256 + threadIdx.x;
    if (i < NPIX) mind[i] = 0xFFFFFFFFu;
}

// ---------------- kernel 4: MFMA GEMM (dist = A.B^T + const) with fused row-min ----------------
// m97 structure: global_load_lds(16B) into linear LDS (pre-swizzled tiles), 2-barrier K-loop.
__global__ __launch_bounds__(256, 2) void k_gemm(const f16_t* __restrict__ A, const f16_t* __restrict__ Bm,
                                                 const float* __restrict__ constl, unsigned* __restrict__ mind) {
    __shared__ __align__(16) f16_t sA[8192];
    __shared__ __align__(16) f16_t sB[8192];

    int bid = blockIdx.x;
    int pid = ((bid & 7) << 7) | (bid >> 3);       // XCD swizzle (1024 % 8 == 0, bijective)
    int group = pid >> 8;
    int pin = pid & 255;
    int bm = group * 8 + (pin & 7);
    int bn = pin >> 3;

    int t = threadIdx.x;
    int lane = t & 63;
    int w = t >> 6;
    int wr = w >> 1, wc = w & 1;

    f32x4 acc[4][4];
    #pragma unroll
    for (int i = 0; i < 4; ++i)
        #pragma unroll
        for (int j = 0; j < 4; ++j) acc[i][j] = (f32x4){0.f, 0.f, 0.f, 0.f};

    const f16_t* Atile = A + (size_t)bm * KSTEPS * 8192;
    const f16_t* Btile = Bm + (size_t)bn * KSTEPS * 8192;

    // per-wave staging: wave w copies chunk set [w*4 .. w*4+3] of each 16KB tile (1KB per issue)
    int chunk0 = w * 2048;           // f16 offset of this wave's 4KB region
    int lofs = lane * 8;             // f16 offset of this lane's 16B within a 1KB chunk

    // precomputed swizzled fragment read offsets (compile-time-friendly)
    int arow[4], brow[4];
    #pragma unroll
    for (int i = 0; i < 4; ++i) {
        arow[i] = wr * 64 + i * 16 + (lane & 15);
        brow[i] = wc * 64 + i * 16 + (lane & 15);
    }

    for (int kt = 0; kt < KSTEPS; ++kt) {
        const f16_t* As = Atile + kt * 8192;
        const f16_t* Bs = Btile + kt * 8192;
        #pragma unroll
        for (int c = 0; c < 4; ++c) {
            gload_lds16(As + chunk0 + c * 512 + lofs, &sA[chunk0 + c * 512]);
            gload_lds16(Bs + chunk0 + c * 512 + lofs, &sB[chunk0 + c * 512]);
        }
        __syncthreads();   // compiler drains vmcnt before s_barrier
        #pragma unroll
        for (int kk = 0; kk < 2; ++kk) {
            f16x8 afr[4], bfr[4];
            int klo = kk * 32 + (lane >> 4) * 8;   // multiple of 8, 0..56
            #pragma unroll
            for (int mi = 0; mi < 4; ++mi)
                afr[mi] = *(const f16x8*)&sA[arow[mi] * 64 + (klo ^ ((arow[mi] & 7) << 3))];
            #pragma unroll
            for (int ni = 0; ni < 4; ++ni)
                bfr[ni] = *(const f16x8*)&sB[brow[ni] * 64 + (klo ^ ((brow[ni] & 7) << 3))];
            #pragma unroll
            for (int mi = 0; mi < 4; ++mi)
                #pragma unroll
                for (int ni = 0; ni < 4; ++ni)
                    acc[mi][ni] = __builtin_amdgcn_mfma_f32_16x16x32_f16(afr[mi], bfr[ni], acc[mi][ni], 0, 0, 0);
        }
        __syncthreads();   // all MFMA fragment reads done before next stage overwrites
    }

    // epilogue: dist = acc + const[col]; min over this block's cols per row; atomicMin
    int colbase = bn * 128 + wc * 64 + (lane & 15);
    float cl[4];
    #pragma unroll
    for (int ni = 0; ni < 4; ++ni) cl[ni] = constl[colbase + ni * 16];
    #pragma unroll
    for (int mi = 0; mi < 4; ++mi) {
        #pragma unroll
        for (int j = 0; j < 4; ++j) {
            float v = 1e30f;
            #pragma unroll
            for (int ni = 0; ni < 4; ++ni) v = fminf(v, acc[mi][ni][j] + cl[ni]);
            #pragma unroll
            for (int s = 1; s < 16; s <<= 1) v = fminf(v, __shfl_xor(v, s, 64));
            if ((lane & 15) == 0) {
                int row = bm * 128 + wr * 64 + mi * 16 + (lane >> 4) * 4 + j;
                atomicMin(&mind[row], f2u(v));
            }
        }
    }
}

// ---------------- kernel 5: global min/max of mind ----------------
__global__ void k_minmax(const unsigned* __restrict__ mind, float* __restrict__ gmm) {
    __shared__ float smin[256], smax[256];
    int t = threadIdx.x;
    float vmin = 1e30f, vmax = -1e30f;
    for (int i = t; i < NPIX; i += 256) {
        float v = u2f(mind[i]);
        vmin = fminf(vmin, v);
        vmax = fmaxf(vmax, v);
    }
    smin[t] = vmin; smax[t] = vmax;
    __syncthreads();
    for (int s = 128; s > 0; s >>= 1) {
        if (t < s) {
            smin[t] = fminf(smin[t], smin[t + s]);
            smax[t] = fmaxf(smax[t], smax[t + s]);
        }
        __syncthreads();
    }
    if (t == 0) { gmm[0] = smin[0]; gmm[1] = smax[0]; }
}

// ---------------- kernel 6: normalize + bilinear upsample 64->256 (float32 output) ----------------
__global__ void k_upsample(const unsigned* __restrict__ mind, const float* __restrict__ gmm,
                           float* __restrict__ out) {
    int gid = blockIdx.x * 256 + threadIdx.x;   // 65536
    int i = gid >> 8, j = gid & 255;
    float gmin = gmm[0];
    float scale = 1.0f / (gmm[1] - gmm[0] + 1e-8f);
    float x = fminf(fmaxf(j * 0.25f - 0.375f, 0.0f), 63.0f);
    float y = fminf(fmaxf(i * 0.25f - 0.375f, 0.0f), 63.0f);
    int x0 = (int)x, y0 = (int)y;
    int x1 = min(x0 + 1, 63), y1 = min(y0 + 1, 63);
    float fx = x - x0, fy = y - y0;
    float v00 = u2f(mind[y0 * 64 + x0]), v01 = u2f(mind[y0 * 64 + x1]);
    float v10 = u2f(mind[y1 * 64 + x0]), v11 = u2f(mind[y1 * 64 + x1]);
    float v = v00 * (1.f - fy) * (1.f - fx) + v01 * (1.f - fy) * fx
            + v10 * fy * (1.f - fx) + v11 * fy * fx;
    out[gid] = (v - gmin) * scale;
}

// ---------------- diagnostic: ws too small -> uniform 0.25 output (absmax ~0.70) ----------------
__global__ void k_diag(float* __restrict__ out) {
    int gid = blockIdx.x * 256 + threadIdx.x;
    out[gid] = 0.25f;
}

extern "C" void kernel_launch(void* const* d_in, const int* in_sizes, int n_in,
                              void* d_out, int out_size, void* d_ws, size_t ws_size,
                              hipStream_t stream) {
    const float* feat = (const float*)d_in[0];
    const float* pw   = (const float*)d_in[1];
    const float* pb   = (const float*)d_in[2];
    const float* mean = (const float*)d_in[3];
    const float* icov = (const float*)d_in[4];

    size_t need = 0;
    auto count = [&need](size_t bytes) { need = ((need + 255) & ~(size_t)255) + bytes; };
    count((size_t)NPIX * DP * 4);
    count((size_t)NPIX * KTOT * 2);
    count((size_t)LNUM * KTOT * 2);
    count((size_t)LNUM * 4);
    count((size_t)NPIX * 4);
    count(2 * 4);
    if (ws_size < need) {
        k_diag<<<256, 256, 0, stream>>>((float*)d_out);
        return;
    }

    char* ws = (char*)d_ws;
    size_t off = 0;
    auto alloc = [&](size_t bytes) -> void* {
        off = (off + 255) & ~(size_t)255;
        void* p = ws + off;
        off += bytes;
        return p;
    };
    float*    f      = (float*)alloc((size_t)NPIX * DP * 4);
    f16_t*    Amat   = (f16_t*)alloc((size_t)NPIX * KTOT * 2);
    f16_t*    Bmat   = (f16_t*)alloc((size_t)LNUM * KTOT * 2);
    float*    constl = (float*)alloc((size_t)LNUM * 4);
    unsigned* mind   = (unsigned*)alloc((size_t)NPIX * 4);
    float*    gmm    = (float*)alloc(2 * 4);

    k_proj    <<<1600, 256, 0, stream>>>(feat, pw, pb, f);
    k_buildA  <<<NPIX, 256, 0, stream>>>(f, Amat);
    k_buildB  <<<LNUM, 256, 0, stream>>>(icov, mean, Bmat, constl);
    k_init    <<<16, 256, 0, stream>>>(mind);
    k_gemm    <<<1024, 256, 0, stream>>>(Amat, Bmat, constl, mind);
    k_minmax  <<<1, 256, 0, stream>>>(mind, gmm);
    k_upsample<<<256, 256, 0, stream>>>(mind, gmm, (float*)d_out);
}

// Round 6
// 292.622 us; speedup vs baseline: 1.3882x; 1.0924x over previous
//
#include <hip/hip_runtime.h>
#include <hip/hip_bf16.h>
#include <stdint.h>

#define CIN   448
#define DP    100
#define NPIX  4096
#define LNUM  4096
#define KQ    5050      // packed upper-triangle columns
#define KLIN  5150      // + 100 linear columns
#define KTOT  5184      // padded to 81*64
#define KSTEPS (KTOT / 64)
#define OUTHW 256

typedef _Float16 f16_t;
typedef _Float16 f16x8 __attribute__((ext_vector_type(8)));
typedef float    f32x4 __attribute__((ext_vector_type(4)));
typedef unsigned short u16x8 __attribute__((ext_vector_type(8)));

static __device__ __forceinline__ int tri_off(int d) { return (d * (201 - d)) >> 1; }

static __device__ __forceinline__ void unpack_tri(int k, int& d, int& e) {
    int dd = (int)((201.0f - sqrtf(40401.0f - 8.0f * (float)k)) * 0.5f);
    if (dd < 0) dd = 0;
    if (dd > 99) dd = 99;
    while (tri_off(dd + 1) <= k) ++dd;
    while (tri_off(dd) > k) --dd;
    d = dd;
    e = dd + (k - tri_off(dd));
}

static __device__ __forceinline__ unsigned f2u(float x) {
    unsigned b = __float_as_uint(x);
    return (b & 0x80000000u) ? ~b : (b | 0x80000000u);
}
static __device__ __forceinline__ float u2f(unsigned u) {
    unsigned b = (u & 0x80000000u) ? (u & 0x7FFFFFFFu) : ~u;
    return __uint_as_float(b);
}

static __device__ __forceinline__ void gload_lds16(const f16_t* g, f16_t* l) {
    __builtin_amdgcn_global_load_lds((const __attribute__((address_space(1))) unsigned*)g,
                                     (__attribute__((address_space(3))) unsigned*)l,
                                     16, 0, 0);
}

// ---------------- kernel 0: tri-unpack LUT (k -> d | e<<8), dummy past KQ ----------------
__global__ void k_lut(unsigned short* __restrict__ lut) {
    int k = blockIdx.x * 256 + threadIdx.x;
    if (k < KTOT) {
        int d = 0, e = 0;
        if (k < KQ) unpack_tri(k, d, e);
        lut[k] = (unsigned short)(d | (e << 8));
    }
}

// ---------------- kernel 1: projection f[n,d] = feat[:,n] . w[d,:] + b[d] ----------------
__global__ void k_proj(const float* __restrict__ feat, const float* __restrict__ w,
                       const float* __restrict__ b, float* __restrict__ f) {
    int gid = blockIdx.x * 256 + threadIdx.x;   // 409600 = 4096*100
    int n = gid & 4095;
    int d = gid >> 12;
    float acc = b[d];
    const float* wd = w + d * CIN;
    #pragma unroll 4
    for (int c = 0; c < CIN; ++c) acc += feat[c * 4096 + n] * wd[c];
    f[n * DP + d] = acc;
}

// ---------------- kernel 2: build A, tiled+swizzled, vectorized stores ----------------
__global__ __launch_bounds__(256) void k_buildA(const float* __restrict__ f, const unsigned short* __restrict__ lut,
                                                f16_t* __restrict__ A) {
    __shared__ float fr[DP];
    int n = blockIdx.x;
    int t = threadIdx.x;
    if (t < DP) fr[t] = f[n * DP + t];
    __syncthreads();
    int r  = n & 127;
    int rsw = (r & 7) << 3;
    f16_t* tileBase = A + (size_t)(n >> 7) * KSTEPS * 8192;
    for (int g = t; g < KTOT / 8; g += 256) {
        int k0 = g * 8;
        u16x8 lu = *(const u16x8*)&lut[k0];
        f16x8 v;
        #pragma unroll
        for (int j = 0; j < 8; ++j) {
            int k = k0 + j;
            float x;
            if (k < KQ) {
                int d = lu[j] & 255, e = lu[j] >> 8;
                x = fr[d] * fr[e];
            } else if (k < KLIN) {
                x = fr[k - KQ];
            } else {
                x = 0.0f;
            }
            v[j] = (f16_t)x;
        }
        int kt = k0 >> 6, kin = k0 & 63;
        *(f16x8*)&tileBase[kt * 8192 + r * 64 + ((kin & 56) ^ rsw)] = v;
    }
}

// ---------------- kernel 3: build B, tiled+swizzled + const[l] ----------------
__global__ __launch_bounds__(256) void k_buildB(const float* __restrict__ icov, const float* __restrict__ mean,
                                                const unsigned short* __restrict__ lut,
                                                f16_t* __restrict__ Bm, float* __restrict__ constl) {
    __shared__ float ic[DP * 101];   // stride 101: conflict-free column reads
    __shared__ float ml[DP];
    __shared__ float wv[DP];
    __shared__ float part[DP];
    int l = blockIdx.x;
    int t = threadIdx.x;
    const float* src = icov + (size_t)l * DP * DP;
    for (int i = t; i < DP * DP; i += 256) {
        int row = i / 100;
        ic[row * 101 + (i - row * 100)] = src[i];
    }
    if (t < DP) ml[t] = mean[t * LNUM + l];
    __syncthreads();
    if (t < DP) {
        float icm = 0.f, ictm = 0.f;
        for (int e = 0; e < DP; ++e) {
            icm  += ic[t * 101 + e] * ml[e];
            ictm += ic[e * 101 + t] * ml[e];
        }
        wv[t]   = icm + ictm;        // (S m)_t  with S = IC + IC^T
        part[t] = ml[t] * icm;       // for m^T IC m
    }
    __syncthreads();
    if (t == 0) {
        float c = 0.f;
        for (int d = 0; d < DP; ++d) c += part[d];
        constl[l] = c;               // m^T IC m
    }
    int r  = l & 127;
    int rsw = (r & 7) << 3;
    f16_t* tileBase = Bm + (size_t)(l >> 7) * KSTEPS * 8192;
    for (int g = t; g < KTOT / 8; g += 256) {
        int k0 = g * 8;
        u16x8 lu = *(const u16x8*)&lut[k0];
        f16x8 v;
        #pragma unroll
        for (int j = 0; j < 8; ++j) {
            int k = k0 + j;
            float x;
            if (k < KQ) {
                int d = lu[j] & 255, e = lu[j] >> 8;
                float s = ic[d * 101 + e] + ic[e * 101 + d];
                x = (d == e) ? 0.5f * s : s;
            } else if (k < KLIN) {
                x = -wv[k - KQ];
            } else {
                x = 0.0f;
            }
            v[j] = (f16_t)x;
        }
        int kt = k0 >> 6, kin = k0 & 63;
        *(f16x8*)&tileBase[kt * 8192 + r * 64 + ((kin & 56) ^ rsw)] = v;
    }
}

// ---------------- kernel 4a: init per-row min ----------------
__global__ void k_init(unsigned* __restrict__ mind) {
    int i = blockIdx.x * 256 + threadIdx.x;
    if (i < NPIX) mind[i] = 0xFFFFFFFFu;
}

// ---------------- kernel 4: 256^2-tile MFMA GEMM, lookahead-1 LDS double-buffer ----------------
// 512 threads = 8 waves (2M x 4N), per-wave 128x64 output. Parity dbuf: stage(kt+1, p^1)
// issued before computing kt on parity p; one barrier per K-step; writes never collide
// with in-flight reads (reads of p^1 finished at the PREVIOUS barrier).
__global__ __launch_bounds__(512, 2) void k_gemm(const f16_t* __restrict__ A, const f16_t* __restrict__ Bm,
                                                 const float* __restrict__ constl, unsigned* __restrict__ mind) {
    __shared__ __align__(16) f16_t sA[2][16384];   // [parity][half 0 | half 1], 64 KB
    __shared__ __align__(16) f16_t sB[2][16384];   // 64 KB

    int bid = blockIdx.x;                           // 256 blocks (16 x 16)
    int pid = ((bid & 7) << 5) | (bid >> 3);        // XCD swizzle, bijective (256 % 8 == 0)
    int bm = pid & 15;
    int bn = pid >> 4;

    int t = threadIdx.x;
    int lane = t & 63;
    int w = t >> 6;                                 // 0..7
    int wr = w >> 2;                                // 0..1 (M)
    int wc = w & 3;                                 // 0..3 (N)

    f32x4 acc[8][4];
    #pragma unroll
    for (int i = 0; i < 8; ++i)
        #pragma unroll
        for (int j = 0; j < 4; ++j) acc[i][j] = (f32x4){0.f, 0.f, 0.f, 0.f};

    // staging geometry: wave w covers f16 range [w*2048, w*2048+2048) of each 32KB operand,
    // 4 issues of (64 lanes x 16B). Half-tile h = w>>2 maps to global tile 2*bm+h / 2*bn+h.
    const f16_t* Abase = A  + ((size_t)(2 * bm + (w >> 2)) * KSTEPS) * 8192 + (w & 3) * 2048 + lane * 8;
    const f16_t* Bbase = Bm + ((size_t)(2 * bn + (w >> 2)) * KSTEPS) * 8192 + (w & 3) * 2048 + lane * 8;

    int l15 = lane & 15;
    int xorv = (lane & 7) << 3;
    int klobase = (lane >> 4) * 8;

    // prologue: stage K-step 0 into parity 0
    {
        const f16_t* As = Abase;
        const f16_t* Bs = Bbase;
        #pragma unroll
        for (int c = 0; c < 4; ++c) {
            gload_lds16(As + c * 512, &sA[0][w * 2048 + c * 512]);
            gload_lds16(Bs + c * 512, &sB[0][w * 2048 + c * 512]);
        }
    }
    __syncthreads();

    for (int kt = 0; kt < KSTEPS; ++kt) {
        int p = kt & 1;
        if (kt + 1 < KSTEPS) {
            const f16_t* As = Abase + (size_t)(kt + 1) * 8192;
            const f16_t* Bs = Bbase + (size_t)(kt + 1) * 8192;
            #pragma unroll
            for (int c = 0; c < 4; ++c) {
                gload_lds16(As + c * 512, &sA[p ^ 1][w * 2048 + c * 512]);
                gload_lds16(Bs + c * 512, &sB[p ^ 1][w * 2048 + c * 512]);
            }
        }
        #pragma unroll
        for (int kk = 0; kk < 2; ++kk) {
            int klo = (kk * 32 + klobase) ^ xorv;
            f16x8 bfr[4];
            #pragma unroll
            for (int ni = 0; ni < 4; ++ni) {
                int rr = (wc & 1) * 64 + ni * 16 + l15;
                bfr[ni] = *(const f16x8*)&sB[p][(wc >> 1) * 8192 + rr * 64 + klo];
            }
            #pragma unroll
            for (int mq = 0; mq < 2; ++mq) {
                f16x8 afr[4];
                #pragma unroll
                for (int mi = 0; mi < 4; ++mi) {
                    int rr = (mq * 4 + mi) * 16 + l15;
                    afr[mi] = *(const f16x8*)&sA[p][wr * 8192 + rr * 64 + klo];
                }
                __builtin_amdgcn_s_setprio(1);
                #pragma unroll
                for (int mi = 0; mi < 4; ++mi)
                    #pragma unroll
                    for (int ni = 0; ni < 4; ++ni)
                        acc[mq * 4 + mi][ni] =
                            __builtin_amdgcn_mfma_f32_16x16x32_f16(afr[mi], bfr[ni], acc[mq * 4 + mi][ni], 0, 0, 0);
                __builtin_amdgcn_s_setprio(0);
            }
        }
        __syncthreads();   // drains vmcnt (stage kt+1 landed) + all reads of parity p done
    }

    // epilogue: dist = acc + const[col]; min over block cols per row; atomicMin
    int colbase = bn * 256 + wc * 64 + l15;
    float cl[4];
    #pragma unroll
    for (int ni = 0; ni < 4; ++ni) cl[ni] = constl[colbase + ni * 16];
    #pragma unroll
    for (int mi8 = 0; mi8 < 8; ++mi8) {
        #pragma unroll
        for (int j = 0; j < 4; ++j) {
            float v = 1e30f;
            #pragma unroll
            for (int ni = 0; ni < 4; ++ni) v = fminf(v, acc[mi8][ni][j] + cl[ni]);
            #pragma unroll
            for (int s = 1; s < 16; s <<= 1) v = fminf(v, __shfl_xor(v, s, 64));
            if (l15 == 0) {
                int row = bm * 256 + wr * 128 + mi8 * 16 + (lane >> 4) * 4 + j;
                atomicMin(&mind[row], f2u(v));
            }
        }
    }
}

// ---------------- kernel 5: global min/max of mind ----------------
__global__ void k_minmax(const unsigned* __restrict__ mind, float* __restrict__ gmm) {
    __shared__ float smin[256], smax[256];
    int t = threadIdx.x;
    float vmin = 1e30f, vmax = -1e30f;
    for (int i = t; i < NPIX; i += 256) {
        float v = u2f(mind[i]);
        vmin = fminf(vmin, v);
        vmax = fmaxf(vmax, v);
    }
    smin[t] = vmin; smax[t] = vmax;
    __syncthreads();
    for (int s = 128; s > 0; s >>= 1) {
        if (t < s) {
            smin[t] = fminf(smin[t], smin[t + s]);
            smax[t] = fmaxf(smax[t], smax[t + s]);
        }
        __syncthreads();
    }
    if (t == 0) { gmm[0] = smin[0]; gmm[1] = smax[0]; }
}

// ---------------- kernel 6: normalize + bilinear upsample 64->256 (float32 output) ----------------
__global__ void k_upsample(const unsigned* __restrict__ mind, const float* __restrict__ gmm,
                           float* __restrict__ out) {
    int gid = blockIdx.x * 256 + threadIdx.x;   // 65536
    int i = gid >> 8, j = gid & 255;
    float gmin = gmm[0];
    float scale = 1.0f / (gmm[1] - gmm[0] + 1e-8f);
    float x = fminf(fmaxf(j * 0.25f - 0.375f, 0.0f), 63.0f);
    float y = fminf(fmaxf(i * 0.25f - 0.375f, 0.0f), 63.0f);
    int x0 = (int)x, y0 = (int)y;
    int x1 = min(x0 + 1, 63), y1 = min(y0 + 1, 63);
    float fx = x - x0, fy = y - y0;
    float v00 = u2f(mind[y0 * 64 + x0]), v01 = u2f(mind[y0 * 64 + x1]);
    float v10 = u2f(mind[y1 * 64 + x0]), v11 = u2f(mind[y1 * 64 + x1]);
    float v = v00 * (1.f - fy) * (1.f - fx) + v01 * (1.f - fy) * fx
            + v10 * fy * (1.f - fx) + v11 * fy * fx;
    out[gid] = (v - gmin) * scale;
}

// ---------------- diagnostic: ws too small -> uniform 0.25 output (absmax ~0.70) ----------------
__global__ void k_diag(float* __restrict__ out) {
    int gid = blockIdx.x * 256 + threadIdx.x;
    out[gid] = 0.25f;
}

extern "C" void kernel_launch(void* const* d_in, const int* in_sizes, int n_in,
                              void* d_out, int out_size, void* d_ws, size_t ws_size,
                              hipStream_t stream) {
    const float* feat = (const float*)d_in[0];
    const float* pw   = (const float*)d_in[1];
    const float* pb   = (const float*)d_in[2];
    const float* mean = (const float*)d_in[3];
    const float* icov = (const float*)d_in[4];

    size_t need = 0;
    auto count = [&need](size_t bytes) { need = ((need + 255) & ~(size_t)255) + bytes; };
    count((size_t)NPIX * DP * 4);
    count((size_t)NPIX * KTOT * 2);
    count((size_t)LNUM * KTOT * 2);
    count((size_t)LNUM * 4);
    count((size_t)NPIX * 4);
    count(2 * 4);
    count((size_t)KTOT * 2);
    if (ws_size < need) {
        k_diag<<<256, 256, 0, stream>>>((float*)d_out);
        return;
    }

    char* ws = (char*)d_ws;
    size_t off = 0;
    auto alloc = [&](size_t bytes) -> void* {
        off = (off + 255) & ~(size_t)255;
        void* p = ws + off;
        off += bytes;
        return p;
    };
    float*          f      = (float*)alloc((size_t)NPIX * DP * 4);
    f16_t*          Amat   = (f16_t*)alloc((size_t)NPIX * KTOT * 2);
    f16_t*          Bmat   = (f16_t*)alloc((size_t)LNUM * KTOT * 2);
    float*          constl = (float*)alloc((size_t)LNUM * 4);
    unsigned*       mind   = (unsigned*)alloc((size_t)NPIX * 4);
    float*          gmm    = (float*)alloc(2 * 4);
    unsigned short* lut    = (unsigned short*)alloc((size_t)KTOT * 2);

    k_lut     <<<(KTOT + 255) / 256, 256, 0, stream>>>(lut);
    k_proj    <<<1600, 256, 0, stream>>>(feat, pw, pb, f);
    k_buildA  <<<NPIX, 256, 0, stream>>>(f, lut, Amat);
    k_buildB  <<<LNUM, 256, 0, stream>>>(icov, mean, lut, Bmat, constl);
    k_init    <<<16, 256, 0, stream>>>(mind);
    k_gemm    <<<256, 512, 0, stream>>>(Amat, Bmat, constl, mind);
    k_minmax  <<<1, 256, 0, stream>>>(mind, gmm);
    k_upsample<<<256, 256, 0, stream>>>(mind, gmm, (float*)d_out);
}